// Round 2
// baseline (1266.241 us; speedup 1.0000x reference)
//
#include <hip/hip_runtime.h>

#define DEV __device__ __forceinline__

DEV float mask_val(const unsigned char* mb, int n) {
  // Detect train_mask storage from its first element: uint8 bool / int32 / float32.
  unsigned b0 = mb[0], b1 = mb[1], b2 = mb[2], b3 = mb[3];
  if (b0 <= 1u && b1 == b0 && b2 == b0 && b3 == b0) {
    return mb[n] ? 1.f : 0.f;                       // 1-byte bool
  } else if (b1 == 0u && b2 == 0u && b3 == 0u) {
    return ((const int*)mb)[n] ? 1.f : 0.f;         // int32
  } else {
    return (((const float*)mb)[n] != 0.f) ? 1.f : 0.f; // float32
  }
}

// ---------------- K0: rank-1 collapses of the context-attention algebra ----------------
__global__ void k_precompute(const float* __restrict__ tf_w, const float* __restrict__ tf_b,
                             const float* __restrict__ deg_w, const float* __restrict__ deg_b,
                             const float* __restrict__ wenc_w, const float* __restrict__ wenc_b,
                             const float* __restrict__ comb_w, float* __restrict__ cbuf) {
  int c = threadIdx.x;  // 64 threads
  float A0 = 0, B0 = 0, A1 = 0, B1 = 0, P0 = 0, Q0 = 0, P1 = 0, Q1 = 0;
  for (int j = 0; j < 64; ++j) {
    float w  = wenc_w[j * 64 + c];
    float cw = comb_w[(64 + j) * 64 + c];
    float twj = tf_w[j], tbj = tf_b[j], dwj = deg_w[j], dbj = deg_b[j];
    A0 += twj * w;  B0 += tbj * w;
    A1 += dwj * w;  B1 += dbj * w;
    P0 += twj * cw; Q0 += tbj * cw;
    P1 += dwj * cw; Q1 += dbj * cw;
  }
  float wb = wenc_b[c];
  cbuf[c]       = A0; cbuf[64 + c]  = B0 + wb;
  cbuf[128 + c] = A1; cbuf[192 + c] = B1 + wb;
  cbuf[256 + c] = P0; cbuf[320 + c] = Q0;
  cbuf[384 + c] = P1; cbuf[448 + c] = Q1;
}

// ---------------- K1: h = relu(x@lin); q_s, k'=k+be, v'=v+be, skip, G = q_s@We^T ----------------
DEV float dot64_bcast(const float4* __restrict__ row, const float* __restrict__ w, float acc) {
#pragma unroll
  for (int j4 = 0; j4 < 16; ++j4) {
    float4 hv = row[j4];
    acc = fmaf(hv.x, w[4 * j4 + 0], acc);
    acc = fmaf(hv.y, w[4 * j4 + 1], acc);
    acc = fmaf(hv.z, w[4 * j4 + 2], acc);
    acc = fmaf(hv.w, w[4 * j4 + 3], acc);
  }
  return acc;
}

__global__ __launch_bounds__(256) void k_node_proj(
    const float* __restrict__ x,
    const float* __restrict__ lin_w, const float* __restrict__ lin_b,
    const float* __restrict__ Wq, const float* __restrict__ bq,
    const float* __restrict__ Wk, const float* __restrict__ bk,
    const float* __restrict__ Wv, const float* __restrict__ bv,
    const float* __restrict__ Wsk, const float* __restrict__ bsk,
    const float* __restrict__ We, const float* __restrict__ be,
    float* __restrict__ q, float* __restrict__ k, float* __restrict__ v,
    float* __restrict__ G, float* __restrict__ skipout, int N) {
  __shared__ float xs[4096];   // x tile; reused as q_s tile for the G stage
  __shared__ float hs[4096];
  const int tid = threadIdx.x;
  const int c = tid & 63;
  const int rr0 = tid >> 6;
  const float invs = 0.17677669529663687f;  // 1/sqrt(32)
  float Gw[32];
#pragma unroll
  for (int j = 0; j < 32; ++j) Gw[j] = We[(c & 31) * 64 + (c >> 5) * 32 + j];
  const float bec = be[c];
  const int ntiles = (N + 63) >> 6;
  for (int tile = blockIdx.x; tile < ntiles; tile += gridDim.x) {
    const int base = tile << 6;
    for (int idx = tid; idx < 4096; idx += 256) {
      int n = base + (idx >> 6);
      xs[idx] = (n < N) ? x[(size_t)n * 64 + (idx & 63)] : 0.f;
    }
    __syncthreads();
    {
      float w[64];
#pragma unroll
      for (int j = 0; j < 64; ++j) w[j] = lin_w[j * 64 + c];
      const float bias = lin_b[c];
      for (int r = rr0; r < 64; r += 4) {
        float acc = dot64_bcast((const float4*)&xs[r << 6], w, bias);
        hs[(r << 6) + c] = fmaxf(acc, 0.f);
      }
    }
    __syncthreads();
    // q stage: q_s = (h@Wq + bq)*invs -> global + LDS (xs reused as qs)
    {
      float w[64];
#pragma unroll
      for (int j = 0; j < 64; ++j) w[j] = Wq[j * 64 + c];
      const float bias = bq[c];
      for (int r = rr0; r < 64; r += 4) {
        const int n = base + r;
        float acc = dot64_bcast((const float4*)&hs[r << 6], w, bias) * invs;
        xs[(r << 6) + c] = acc;
        if (n < N) q[(size_t)n * 64 + c] = acc;
      }
    }
    // k' = h@Wk + bk + be
    {
      float w[64];
#pragma unroll
      for (int j = 0; j < 64; ++j) w[j] = Wk[j * 64 + c];
      const float bias = bk[c] + bec;
      for (int r = rr0; r < 64; r += 4) {
        const int n = base + r;
        float acc = dot64_bcast((const float4*)&hs[r << 6], w, bias);
        if (n < N) k[(size_t)n * 64 + c] = acc;
      }
    }
    // v' = h@Wv + bv + be
    {
      float w[64];
#pragma unroll
      for (int j = 0; j < 64; ++j) w[j] = Wv[j * 64 + c];
      const float bias = bv[c] + bec;
      for (int r = rr0; r < 64; r += 4) {
        const int n = base + r;
        float acc = dot64_bcast((const float4*)&hs[r << 6], w, bias);
        if (n < N) v[(size_t)n * 64 + c] = acc;
      }
    }
    // skip = h@Wskip + bskip  (staged into d_out[0:N*64))
    {
      float w[64];
#pragma unroll
      for (int j = 0; j < 64; ++j) w[j] = Wsk[j * 64 + c];
      const float bias = bsk[c];
      for (int r = rr0; r < 64; r += 4) {
        const int n = base + r;
        float acc = dot64_bcast((const float4*)&hs[r << 6], w, bias);
        if (n < N) skipout[(size_t)n * 64 + c] = acc;
      }
    }
    __syncthreads();  // qs (xs) fully written
    // G[n, h*32+j] = sum_{c'} q_s[n, h*32+c'] * We[j, h*32+c']
    {
      for (int r = rr0; r < 64; r += 4) {
        const int n = base + r;
        const float* qrow = &xs[(r << 6) + (c >> 5) * 32];
        float g = 0.f;
#pragma unroll
        for (int j4 = 0; j4 < 8; ++j4) {
          float4 qv = ((const float4*)qrow)[j4];
          g = fmaf(qv.x, Gw[4 * j4 + 0], g);
          g = fmaf(qv.y, Gw[4 * j4 + 1], g);
          g = fmaf(qv.z, Gw[4 * j4 + 2], g);
          g = fmaf(qv.w, Gw[4 * j4 + 3], g);
        }
        if (n < N) G[(size_t)n * 64 + c] = g;
      }
    }
    __syncthreads();
  }
}

// ---------------- CSR build ----------------
__global__ __launch_bounds__(256) void k_hist(const int* __restrict__ ei, int* __restrict__ counts, int E) {
  int i = blockIdx.x * 256 + threadIdx.x;
  if (i < E) atomicAdd(&counts[ei[E + i]], 1);
}

__global__ __launch_bounds__(256) void k_scan1(const int* __restrict__ counts, int* __restrict__ excl,
                                               int* __restrict__ bsum, int N) {
  __shared__ int s[256];
  const int t = threadIdx.x;
  const int idx = blockIdx.x * 256 + t;
  int val = (idx < N) ? counts[idx] : 0;
  s[t] = val;
  __syncthreads();
  for (int d = 1; d < 256; d <<= 1) {
    int add = (t >= d) ? s[t - d] : 0;
    __syncthreads();
    s[t] += add;
    __syncthreads();
  }
  if (idx < N) excl[idx] = s[t] - val;
  if (t == 255) bsum[blockIdx.x] = s[255];
}

__global__ void k_scan2(int* __restrict__ bsum, int B) {
  if (threadIdx.x == 0) {
    int acc = 0;
    for (int i = 0; i < B; ++i) { int t = bsum[i]; bsum[i] = acc; acc += t; }
  }
}

__global__ __launch_bounds__(256) void k_scan3(const int* __restrict__ bsum, int* __restrict__ rowptr,
                                               int* __restrict__ next, int N, int E) {
  int i = blockIdx.x * 256 + threadIdx.x;
  if (i < N) {
    int r = rowptr[i] + bsum[i >> 8];
    rowptr[i] = r;
    next[i] = r;
  }
  if (i == 0) rowptr[N] = E;
}

__global__ __launch_bounds__(256) void k_fill(const int* __restrict__ ei,
                                              const float* __restrict__ node_time,
                                              const float* __restrict__ edge_time,
                                              int* __restrict__ next, int* __restrict__ srcs,
                                              float* __restrict__ rels, int E) {
  int e = blockIdx.x * 256 + threadIdx.x;
  if (e < E) {
    int s = ei[e], d = ei[E + e];
    int pos = atomicAdd(&next[d], 1);
    srcs[pos] = s;
    rels[pos] = node_time[s] - edge_time[e];
  }
}

// ---------------- K2: CSR gather + online softmax aggregate ----------------
// one wave per dst node; lane = channel; alpha = q_s.k' + rv*G (shfl-reduced per head);
// e-projection's V contribution factored through S_j = sum_e ea_e*rv_j, applied once per node.
__global__ __launch_bounds__(256) void k_aggregate(
    const int* __restrict__ rowptr, const int* __restrict__ srcs, const float* __restrict__ rels,
    const float* __restrict__ q, const float* __restrict__ k, const float* __restrict__ v,
    const float* __restrict__ G,
    const float* __restrict__ time_w, const float* __restrict__ time_b,
    const float* __restrict__ We,
    float* __restrict__ h1, int N) {
  __shared__ float swS[4][64];
  const int tid = threadIdx.x;
  const int c = tid & 63;
  const int wv = tid >> 6;
  const float INV2PI = 0.15915494309189535f;
  float wcol[32];
#pragma unroll
  for (int j = 0; j < 32; ++j) wcol[j] = We[j * 64 + c];
  const float tw = time_w[c & 31] * INV2PI;
  const float tb = time_b[c & 31] * INV2PI;
  const int n0 = blockIdx.x * 4 + wv;
  const int nstride = gridDim.x * 4;
  for (int n = n0; n < N; n += nstride) {
    const int start = rowptr[n];
    const int end = rowptr[n + 1];
    const float qc = q[(size_t)n * 64 + c];
    const float Gc = G[(size_t)n * 64 + c];
    float m = -1e30f, den = 0.f, num = 0.f, S = 0.f;
    // 2-deep pipeline: regs A = edge e (kv/vv/rel ready); B = (src,rel) of e+1
    float relA = 0.f, kvA = 0.f, vvA = 0.f, relB = 0.f;
    int srcB = 0;
    if (start < end) {
      int s0 = srcs[start];
      relA = rels[start];
      kvA = k[(size_t)s0 * 64 + c];
      vvA = v[(size_t)s0 * 64 + c];
    }
    if (start + 1 < end) { srcB = srcs[start + 1]; relB = rels[start + 1]; }
    for (int e = start; e < end; ++e) {
      float kvB = 0.f, vvB = 0.f, relC = 0.f;
      int srcC = 0;
      if (e + 1 < end) {
        kvB = k[(size_t)srcB * 64 + c];
        vvB = v[(size_t)srcB * 64 + c];
      }
      if (e + 2 < end) { srcC = srcs[e + 2]; relC = rels[e + 2]; }
      // compute edge e
      float ang = fmaf(relA, tw, tb);
      ang = ang - floorf(ang);
      const float rv = __builtin_amdgcn_cosf(ang);   // cos(2*pi*ang)
      float p = fmaf(rv, Gc, qc * kvA);
#pragma unroll
      for (int msk = 16; msk >= 1; msk >>= 1) p += __shfl_xor(p, msk, 64);
      const float mn = fmaxf(m, p);
      const float sc = __expf(m - mn);
      const float ea = __expf(p - mn);
      num = fmaf(num, sc, ea * vvA);
      S   = fmaf(S, sc, ea * rv);
      den = fmaf(den, sc, ea);
      m = mn;
      // rotate pipeline
      relA = relB; kvA = kvB; vvA = vvB;
      srcB = srcC; relB = relC;
    }
    // e-projection contribution: econ[c] = sum_j We[j,c] * S[head(c)*32 + j]
    swS[wv][c] = S;
    float econ = 0.f;
#pragma unroll
    for (int j = 0; j < 32; ++j) econ = fmaf(swS[wv][(c & 32) | j], wcol[j], econ);
    const float agg = (num + econ) / (den + 1e-16f);
    h1[(size_t)n * 64 + c] = agg + h1[(size_t)n * 64 + c];  // + staged skip
  }
}

// ---------------- K4: epilogue (context attention + combine + out + log_softmax) ----------------
__global__ __launch_bounds__(256) void k_epilogue(
    const float* __restrict__ t_int, const float* __restrict__ deg,
    const float* __restrict__ cbuf,
    const float* __restrict__ wx_w, const float* __restrict__ wx_b,
    const float* __restrict__ comb_w, const float* __restrict__ comb_b,
    const float* __restrict__ out_w, const float* __restrict__ out_b,
    const int* __restrict__ y, const unsigned char* __restrict__ maskb,
    float* __restrict__ out, int N) {
  __shared__ float sh[4][64];
  const int tid = threadIdx.x;
  const int c = tid & 63;
  const int wv = tid >> 6;
  float wxreg[64], cbreg[64];
#pragma unroll
  for (int j = 0; j < 64; ++j) { wxreg[j] = wx_w[j * 64 + c]; cbreg[j] = comb_w[j * 64 + c]; }
  const float A0 = cbuf[c], B0 = cbuf[64 + c], A1 = cbuf[128 + c], B1 = cbuf[192 + c];
  const float P0 = cbuf[256 + c], Q0 = cbuf[320 + c], P1 = cbuf[384 + c], Q1 = cbuf[448 + c];
  const float wxb = wx_b[c], cbb = comb_b[c];
  const float ow0 = out_w[c * 2 + 0], ow1 = out_w[c * 2 + 1];
  const float ob0 = out_b[0], ob1 = out_b[1];
  const size_t O1 = (size_t)N * 64;
  const size_t O2 = O1 + (size_t)N * 2;
  const size_t O3 = O2 + (size_t)N;
  const int ngroups = (N + 3) >> 2;
  for (int g = blockIdx.x; g < ngroups; g += gridDim.x) {
    const int n = g * 4 + wv;
    const bool act = n < N;
    float h1a = 0.f, ti = 0.f, dg = 0.f;
    if (act) {
      h1a = out[(size_t)n * 64 + c];  // agg + skip, staged by k_aggregate
      ti = t_int[n];
      dg = deg[n];
    }
    sh[wv][c] = h1a;
    __syncthreads();
    const float4* hr = (const float4*)&sh[wv][0];
    float xp = wxb;
    float acc = cbb;
#pragma unroll
    for (int j4 = 0; j4 < 16; ++j4) {
      float4 hv = hr[j4];
      xp  = fmaf(hv.x, wxreg[4 * j4 + 0], xp);
      xp  = fmaf(hv.y, wxreg[4 * j4 + 1], xp);
      xp  = fmaf(hv.z, wxreg[4 * j4 + 2], xp);
      xp  = fmaf(hv.w, wxreg[4 * j4 + 3], xp);
      acc = fmaf(hv.x, cbreg[4 * j4 + 0], acc);
      acc = fmaf(hv.y, cbreg[4 * j4 + 1], acc);
      acc = fmaf(hv.z, cbreg[4 * j4 + 2], acc);
      acc = fmaf(hv.w, cbreg[4 * j4 + 3], acc);
    }
    xp = tanhf(xp);
    const float ep0 = tanhf(fmaf(ti, A0, B0));
    const float ep1 = tanhf(fmaf(dg, A1, B1));
    float d0 = ep0 * xp, d1 = ep1 * xp;
#pragma unroll
    for (int msk = 32; msk >= 1; msk >>= 1) { d0 += __shfl_xor(d0, msk, 64); d1 += __shfl_xor(d1, msk, 64); }
    const float mx = fmaxf(d0, d1);
    const float e0 = expf(d0 - mx), e1 = expf(d1 - mx);
    const float sden = e0 + e1;
    const float s0 = e0 / sden, s1 = e1 / sden;
    acc = fmaf(s0, fmaf(ti, P0, Q0), acc);
    acc = fmaf(s1, fmaf(dg, P1, Q1), acc);
    float z0 = acc * ow0, z1 = acc * ow1;
#pragma unroll
    for (int msk = 32; msk >= 1; msk >>= 1) { z0 += __shfl_xor(z0, msk, 64); z1 += __shfl_xor(z1, msk, 64); }
    if (act) {
      out[(size_t)n * 64 + c] = acc;  // final h1
      if (c == 0) {
        z0 += ob0; z1 += ob1;
        const float mz = fmaxf(z0, z1);
        const float lse = mz + logf(expf(z0 - mz) + expf(z1 - mz));
        out[O1 + (size_t)n * 2 + 0] = z0 - lse;
        out[O1 + (size_t)n * 2 + 1] = z1 - lse;
        out[O2 + (size_t)n] = (float)y[n];
        out[O3 + (size_t)n] = mask_val(maskb, n);
      }
    }
    __syncthreads();
  }
}

extern "C" void kernel_launch(void* const* d_in, const int* in_sizes, int n_in,
                              void* d_out, int out_size, void* d_ws, size_t ws_size,
                              hipStream_t stream) {
  const float* x          = (const float*)d_in[0];
  const int*   ei         = (const int*)d_in[1];
  const float* node_time  = (const float*)d_in[2];
  const float* edge_time  = (const float*)d_in[3];
  const float* nmoti      = (const float*)d_in[4];
  const float* nod        = (const float*)d_in[5];
  const int*   y          = (const int*)d_in[6];
  const unsigned char* mask = (const unsigned char*)d_in[7];
  const float* time_w = (const float*)d_in[8];
  const float* time_b = (const float*)d_in[9];
  const float* tf_w   = (const float*)d_in[10];
  const float* tf_b   = (const float*)d_in[11];
  const float* deg_w  = (const float*)d_in[12];
  const float* deg_b  = (const float*)d_in[13];
  const float* lin_w  = (const float*)d_in[14];
  const float* lin_b  = (const float*)d_in[15];
  const float* Wq     = (const float*)d_in[16];
  const float* bq     = (const float*)d_in[17];
  const float* Wk     = (const float*)d_in[18];
  const float* bk     = (const float*)d_in[19];
  const float* Wv     = (const float*)d_in[20];
  const float* bv     = (const float*)d_in[21];
  const float* We     = (const float*)d_in[22];
  const float* be     = (const float*)d_in[23];
  const float* Wsk    = (const float*)d_in[24];
  const float* bsk    = (const float*)d_in[25];
  const float* wenc_w = (const float*)d_in[26];
  const float* wenc_b = (const float*)d_in[27];
  const float* wx_w   = (const float*)d_in[28];
  const float* wx_b   = (const float*)d_in[29];
  const float* comb_w = (const float*)d_in[30];
  const float* comb_b = (const float*)d_in[31];
  const float* out_w  = (const float*)d_in[32];
  const float* out_b  = (const float*)d_in[33];

  const int N = in_sizes[2];   // node_time
  const int E = in_sizes[3];   // edge_time
  const size_t N64 = (size_t)N * 64;

  float* q    = (float*)d_ws;
  float* k    = q + N64;
  float* v    = k + N64;
  float* G    = v + N64;
  float* rels = G + N64;
  int*   srcs = (int*)(rels + E);
  int*   counts = srcs + E;
  int*   rowptr = counts + N;        // N+1 ints
  int*   next   = rowptr + N + 1;
  int*   bsum   = next + N;          // ceil(N/256) ints (padded)
  float* cbuf   = (float*)(bsum + 4096);
  float* outf   = (float*)d_out;
  float* skip   = outf;  // stage skip in d_out[0:N*64)

  const int B = (N + 255) / 256;

  hipMemsetAsync(counts, 0, (size_t)N * sizeof(int), stream);

  k_precompute<<<1, 64, 0, stream>>>(tf_w, tf_b, deg_w, deg_b, wenc_w, wenc_b, comb_w, cbuf);

  const int ntiles = (N + 63) >> 6;
  k_node_proj<<<ntiles, 256, 0, stream>>>(x, lin_w, lin_b, Wq, bq, Wk, bk, Wv, bv, Wsk, bsk,
                                          We, be, q, k, v, G, skip, N);

  const int EB = (E + 255) / 256;
  k_hist<<<EB, 256, 0, stream>>>(ei, counts, E);
  k_scan1<<<B, 256, 0, stream>>>(counts, rowptr, bsum, N);
  k_scan2<<<1, 64, 0, stream>>>(bsum, B);
  k_scan3<<<B, 256, 0, stream>>>(bsum, rowptr, next, N, E);
  k_fill<<<EB, 256, 0, stream>>>(ei, node_time, edge_time, next, srcs, rels, E);

  k_aggregate<<<(N + 3) / 4, 256, 0, stream>>>(rowptr, srcs, rels, q, k, v, G,
                                               time_w, time_b, We, outf, N);

  k_epilogue<<<2048, 256, 0, stream>>>(nmoti, nod, cbuf, wx_w, wx_b,
                                       comb_w, comb_b, out_w, out_b, y, mask, outf, N);
}

// Round 3
// 760.943 us; speedup vs baseline: 1.6640x; 1.6640x over previous
//
#include <hip/hip_runtime.h>

#define DEV __device__ __forceinline__

DEV float mask_val(const unsigned char* mb, int n) {
  // Detect train_mask storage from its first element: uint8 bool / int32 / float32.
  unsigned b0 = mb[0], b1 = mb[1], b2 = mb[2], b3 = mb[3];
  if (b0 <= 1u && b1 == b0 && b2 == b0 && b3 == b0) {
    return mb[n] ? 1.f : 0.f;                       // 1-byte bool
  } else if (b1 == 0u && b2 == 0u && b3 == 0u) {
    return ((const int*)mb)[n] ? 1.f : 0.f;         // int32
  } else {
    return (((const float*)mb)[n] != 0.f) ? 1.f : 0.f; // float32
  }
}

// ---------------- K0: rank-1 collapses of the context-attention algebra ----------------
__global__ void k_precompute(const float* __restrict__ tf_w, const float* __restrict__ tf_b,
                             const float* __restrict__ deg_w, const float* __restrict__ deg_b,
                             const float* __restrict__ wenc_w, const float* __restrict__ wenc_b,
                             const float* __restrict__ comb_w, float* __restrict__ cbuf) {
  int c = threadIdx.x;  // 64 threads
  float A0 = 0, B0 = 0, A1 = 0, B1 = 0, P0 = 0, Q0 = 0, P1 = 0, Q1 = 0;
  for (int j = 0; j < 64; ++j) {
    float w  = wenc_w[j * 64 + c];
    float cw = comb_w[(64 + j) * 64 + c];
    float twj = tf_w[j], tbj = tf_b[j], dwj = deg_w[j], dbj = deg_b[j];
    A0 += twj * w;  B0 += tbj * w;
    A1 += dwj * w;  B1 += dbj * w;
    P0 += twj * cw; Q0 += tbj * cw;
    P1 += dwj * cw; Q1 += dbj * cw;
  }
  float wb = wenc_b[c];
  cbuf[c]       = A0; cbuf[64 + c]  = B0 + wb;
  cbuf[128 + c] = A1; cbuf[192 + c] = B1 + wb;
  cbuf[256 + c] = P0; cbuf[320 + c] = Q0;
  cbuf[384 + c] = P1; cbuf[448 + c] = Q1;
}

// ---------------- K1: h = relu(x@lin); q, k'=k+be, v'=v+be, skip ----------------
// lane = output channel; ONE w[64] column array, reused across stages via unroll-1 loop.
DEV float dot64_bcast(const float4* __restrict__ row, const float* __restrict__ w, float acc) {
#pragma unroll
  for (int j4 = 0; j4 < 16; ++j4) {
    float4 hv = row[j4];
    acc = fmaf(hv.x, w[4 * j4 + 0], acc);
    acc = fmaf(hv.y, w[4 * j4 + 1], acc);
    acc = fmaf(hv.z, w[4 * j4 + 2], acc);
    acc = fmaf(hv.w, w[4 * j4 + 3], acc);
  }
  return acc;
}

__global__ __launch_bounds__(256) void k_node_proj(
    const float* __restrict__ x,
    const float* __restrict__ lin_w, const float* __restrict__ lin_b,
    const float* __restrict__ Wq, const float* __restrict__ bq,
    const float* __restrict__ Wk, const float* __restrict__ bk,
    const float* __restrict__ Wv, const float* __restrict__ bv,
    const float* __restrict__ Wsk, const float* __restrict__ bsk,
    const float* __restrict__ be,
    float* __restrict__ q, float* __restrict__ k, float* __restrict__ v,
    float* __restrict__ skipout, int N) {
  __shared__ float xs[4096];
  __shared__ float hs[4096];
  const int tid = threadIdx.x;
  const int c = tid & 63;
  const int rr0 = tid >> 6;
  const float bec = be[c];
  const int ntiles = (N + 63) >> 6;
  for (int tile = blockIdx.x; tile < ntiles; tile += gridDim.x) {
    const int base = tile << 6;
    for (int idx = tid; idx < 4096; idx += 256) {
      int n = base + (idx >> 6);
      xs[idx] = (n < N) ? x[(size_t)n * 64 + (idx & 63)] : 0.f;
    }
    __syncthreads();
    {
      float w[64];
#pragma unroll
      for (int j = 0; j < 64; ++j) w[j] = lin_w[j * 64 + c];
      const float bias = lin_b[c];
      for (int r = rr0; r < 64; r += 4) {
        float acc = dot64_bcast((const float4*)&xs[r << 6], w, bias);
        hs[(r << 6) + c] = fmaxf(acc, 0.f);
      }
    }
    __syncthreads();
    const float* Wm[4] = {Wq, Wk, Wv, Wsk};
    const float* bm[4] = {bq, bk, bv, bsk};
    float* om[4] = {q, k, v, skipout};
#pragma unroll 1
    for (int mm = 0; mm < 4; ++mm) {
      float w[64];
#pragma unroll
      for (int j = 0; j < 64; ++j) w[j] = Wm[mm][j * 64 + c];
      const float bias = bm[mm][c] + ((mm == 1 || mm == 2) ? bec : 0.f);
      for (int r = rr0; r < 64; r += 4) {
        const int n = base + r;
        float acc = dot64_bcast((const float4*)&hs[r << 6], w, bias);
        if (n < N) om[mm][(size_t)n * 64 + c] = acc;
      }
    }
    __syncthreads();
  }
}

// ---------------- CSR build ----------------
__global__ __launch_bounds__(256) void k_hist(const int* __restrict__ ei, int* __restrict__ counts, int E) {
  int i = blockIdx.x * 256 + threadIdx.x;
  if (i < E) atomicAdd(&counts[ei[E + i]], 1);
}

__global__ __launch_bounds__(256) void k_scan1(const int* __restrict__ counts, int* __restrict__ excl,
                                               int* __restrict__ bsum, int N) {
  __shared__ int s[256];
  const int t = threadIdx.x;
  const int idx = blockIdx.x * 256 + t;
  int val = (idx < N) ? counts[idx] : 0;
  s[t] = val;
  __syncthreads();
  for (int d = 1; d < 256; d <<= 1) {
    int add = (t >= d) ? s[t - d] : 0;
    __syncthreads();
    s[t] += add;
    __syncthreads();
  }
  if (idx < N) excl[idx] = s[t] - val;
  if (t == 255) bsum[blockIdx.x] = s[255];
}

__global__ void k_scan2(int* __restrict__ bsum, int B) {
  if (threadIdx.x == 0) {
    int acc = 0;
    for (int i = 0; i < B; ++i) { int t = bsum[i]; bsum[i] = acc; acc += t; }
  }
}

__global__ __launch_bounds__(256) void k_scan3(const int* __restrict__ bsum, int* __restrict__ rowptr,
                                               int* __restrict__ next, int N, int E) {
  int i = blockIdx.x * 256 + threadIdx.x;
  if (i < N) {
    int r = rowptr[i] + bsum[i >> 8];
    rowptr[i] = r;
    next[i] = r;
  }
  if (i == 0) rowptr[N] = E;
}

__global__ __launch_bounds__(256) void k_fill(const int* __restrict__ ei,
                                              const float* __restrict__ node_time,
                                              const float* __restrict__ edge_time,
                                              int* __restrict__ next, int* __restrict__ srcs,
                                              float* __restrict__ rels, int E) {
  int e = blockIdx.x * 256 + threadIdx.x;
  if (e < E) {
    int s = ei[e], d = ei[E + e];
    int pos = atomicAdd(&next[d], 1);
    srcs[pos] = s;
    rels[pos] = node_time[s] - edge_time[e];
  }
}

// ---------------- K2: CSR gather + online softmax aggregate ----------------
// one wave per dst node; lane = channel; alpha = q_s.k' + rv*G (shfl-reduced per head);
// G = q_s@We^T computed per node from the LDS-staged q row (Gw register column);
// e-projection's V contribution factored through S_j = sum_e ea_e*rv_j, applied once per node.
__global__ __launch_bounds__(256) void k_aggregate(
    const int* __restrict__ rowptr, const int* __restrict__ srcs, const float* __restrict__ rels,
    const float* __restrict__ q, const float* __restrict__ k, const float* __restrict__ v,
    const float* __restrict__ time_w, const float* __restrict__ time_b,
    const float* __restrict__ We,
    float* __restrict__ h1, int N) {
  __shared__ float swS[4][64];
  const int tid = threadIdx.x;
  const int c = tid & 63;
  const int wv = tid >> 6;
  const float INV2PI = 0.15915494309189535f;
  const float invs = 0.17677669529663687f;  // 1/sqrt(32)
  float wcol[32], Gw[32];
#pragma unroll
  for (int j = 0; j < 32; ++j) wcol[j] = We[j * 64 + c];
#pragma unroll
  for (int j = 0; j < 32; ++j) Gw[j] = We[(c & 31) * 64 + (c & 32) + j];
  const float tw = time_w[c & 31] * INV2PI;
  const float tb = time_b[c & 31] * INV2PI;
  const int n0 = blockIdx.x * 4 + wv;
  const int nstride = gridDim.x * 4;
  for (int n = n0; n < N; n += nstride) {
    const int start = rowptr[n];
    const int end = rowptr[n + 1];
    const float qc = q[(size_t)n * 64 + c] * invs;
    // G[c] = sum_{c'} q_s[n, head(c)*32+c'] * We[c&31, head(c)*32+c']  (broadcast LDS reads)
    swS[wv][c] = qc;
    float Gc = 0.f;
#pragma unroll
    for (int j = 0; j < 32; ++j) Gc = fmaf(swS[wv][(c & 32) | j], Gw[j], Gc);
    float m = -1e30f, den = 0.f, num = 0.f, S = 0.f;
    // 2-deep pipeline: regs A = edge e (kv/vv/rel ready); B = (src,rel) of e+1
    float relA = 0.f, kvA = 0.f, vvA = 0.f, relB = 0.f;
    int srcB = 0;
    if (start < end) {
      int s0 = srcs[start];
      relA = rels[start];
      kvA = k[(size_t)s0 * 64 + c];
      vvA = v[(size_t)s0 * 64 + c];
    }
    if (start + 1 < end) { srcB = srcs[start + 1]; relB = rels[start + 1]; }
    for (int e = start; e < end; ++e) {
      float kvB = 0.f, vvB = 0.f, relC = 0.f;
      int srcC = 0;
      if (e + 1 < end) {
        kvB = k[(size_t)srcB * 64 + c];
        vvB = v[(size_t)srcB * 64 + c];
      }
      if (e + 2 < end) { srcC = srcs[e + 2]; relC = rels[e + 2]; }
      // compute edge e
      float ang = fmaf(relA, tw, tb);
      ang = ang - floorf(ang);
      const float rv = __builtin_amdgcn_cosf(ang);   // cos(2*pi*ang)
      float p = fmaf(rv, Gc, qc * kvA);
#pragma unroll
      for (int msk = 16; msk >= 1; msk >>= 1) p += __shfl_xor(p, msk, 64);
      const float mn = fmaxf(m, p);
      const float sc = __expf(m - mn);
      const float ea = __expf(p - mn);
      num = fmaf(num, sc, ea * vvA);
      S   = fmaf(S, sc, ea * rv);
      den = fmaf(den, sc, ea);
      m = mn;
      // rotate pipeline
      relA = relB; kvA = kvB; vvA = vvB;
      srcB = srcC; relB = relC;
    }
    // e-projection contribution: econ[c] = sum_j We[j,c] * S[head(c)*32 + j]
    swS[wv][c] = S;
    float econ = 0.f;
#pragma unroll
    for (int j = 0; j < 32; ++j) econ = fmaf(swS[wv][(c & 32) | j], wcol[j], econ);
    const float agg = (num + econ) / (den + 1e-16f);
    h1[(size_t)n * 64 + c] = agg + h1[(size_t)n * 64 + c];  // + staged skip
  }
}

// ---------------- K4: epilogue (context attention + combine + out + log_softmax) ----------------
__global__ __launch_bounds__(256) void k_epilogue(
    const float* __restrict__ t_int, const float* __restrict__ deg,
    const float* __restrict__ cbuf,
    const float* __restrict__ wx_w, const float* __restrict__ wx_b,
    const float* __restrict__ comb_w, const float* __restrict__ comb_b,
    const float* __restrict__ out_w, const float* __restrict__ out_b,
    const int* __restrict__ y, const unsigned char* __restrict__ maskb,
    float* __restrict__ out, int N) {
  __shared__ float sh[4][64];
  const int tid = threadIdx.x;
  const int c = tid & 63;
  const int wv = tid >> 6;
  float wxreg[64], cbreg[64];
#pragma unroll
  for (int j = 0; j < 64; ++j) { wxreg[j] = wx_w[j * 64 + c]; cbreg[j] = comb_w[j * 64 + c]; }
  const float A0 = cbuf[c], B0 = cbuf[64 + c], A1 = cbuf[128 + c], B1 = cbuf[192 + c];
  const float P0 = cbuf[256 + c], Q0 = cbuf[320 + c], P1 = cbuf[384 + c], Q1 = cbuf[448 + c];
  const float wxb = wx_b[c], cbb = comb_b[c];
  const float ow0 = out_w[c * 2 + 0], ow1 = out_w[c * 2 + 1];
  const float ob0 = out_b[0], ob1 = out_b[1];
  const size_t O1 = (size_t)N * 64;
  const size_t O2 = O1 + (size_t)N * 2;
  const size_t O3 = O2 + (size_t)N;
  const int ngroups = (N + 3) >> 2;
  for (int g = blockIdx.x; g < ngroups; g += gridDim.x) {
    const int n = g * 4 + wv;
    const bool act = n < N;
    float h1a = 0.f, ti = 0.f, dg = 0.f;
    if (act) {
      h1a = out[(size_t)n * 64 + c];  // agg + skip, staged by k_aggregate
      ti = t_int[n];
      dg = deg[n];
    }
    sh[wv][c] = h1a;
    __syncthreads();
    const float4* hr = (const float4*)&sh[wv][0];
    float xp = wxb;
    float acc = cbb;
#pragma unroll
    for (int j4 = 0; j4 < 16; ++j4) {
      float4 hv = hr[j4];
      xp  = fmaf(hv.x, wxreg[4 * j4 + 0], xp);
      xp  = fmaf(hv.y, wxreg[4 * j4 + 1], xp);
      xp  = fmaf(hv.z, wxreg[4 * j4 + 2], xp);
      xp  = fmaf(hv.w, wxreg[4 * j4 + 3], xp);
      acc = fmaf(hv.x, cbreg[4 * j4 + 0], acc);
      acc = fmaf(hv.y, cbreg[4 * j4 + 1], acc);
      acc = fmaf(hv.z, cbreg[4 * j4 + 2], acc);
      acc = fmaf(hv.w, cbreg[4 * j4 + 3], acc);
    }
    xp = tanhf(xp);
    const float ep0 = tanhf(fmaf(ti, A0, B0));
    const float ep1 = tanhf(fmaf(dg, A1, B1));
    float d0 = ep0 * xp, d1 = ep1 * xp;
#pragma unroll
    for (int msk = 32; msk >= 1; msk >>= 1) { d0 += __shfl_xor(d0, msk, 64); d1 += __shfl_xor(d1, msk, 64); }
    const float mx = fmaxf(d0, d1);
    const float e0 = expf(d0 - mx), e1 = expf(d1 - mx);
    const float sden = e0 + e1;
    const float s0 = e0 / sden, s1 = e1 / sden;
    acc = fmaf(s0, fmaf(ti, P0, Q0), acc);
    acc = fmaf(s1, fmaf(dg, P1, Q1), acc);
    float z0 = acc * ow0, z1 = acc * ow1;
#pragma unroll
    for (int msk = 32; msk >= 1; msk >>= 1) { z0 += __shfl_xor(z0, msk, 64); z1 += __shfl_xor(z1, msk, 64); }
    if (act) {
      out[(size_t)n * 64 + c] = acc;  // final h1
      if (c == 0) {
        z0 += ob0; z1 += ob1;
        const float mz = fmaxf(z0, z1);
        const float lse = mz + logf(expf(z0 - mz) + expf(z1 - mz));
        out[O1 + (size_t)n * 2 + 0] = z0 - lse;
        out[O1 + (size_t)n * 2 + 1] = z1 - lse;
        out[O2 + (size_t)n] = (float)y[n];
        out[O3 + (size_t)n] = mask_val(maskb, n);
      }
    }
    __syncthreads();
  }
}

extern "C" void kernel_launch(void* const* d_in, const int* in_sizes, int n_in,
                              void* d_out, int out_size, void* d_ws, size_t ws_size,
                              hipStream_t stream) {
  const float* x          = (const float*)d_in[0];
  const int*   ei         = (const int*)d_in[1];
  const float* node_time  = (const float*)d_in[2];
  const float* edge_time  = (const float*)d_in[3];
  const float* nmoti      = (const float*)d_in[4];
  const float* nod        = (const float*)d_in[5];
  const int*   y          = (const int*)d_in[6];
  const unsigned char* mask = (const unsigned char*)d_in[7];
  const float* time_w = (const float*)d_in[8];
  const float* time_b = (const float*)d_in[9];
  const float* tf_w   = (const float*)d_in[10];
  const float* tf_b   = (const float*)d_in[11];
  const float* deg_w  = (const float*)d_in[12];
  const float* deg_b  = (const float*)d_in[13];
  const float* lin_w  = (const float*)d_in[14];
  const float* lin_b  = (const float*)d_in[15];
  const float* Wq     = (const float*)d_in[16];
  const float* bq     = (const float*)d_in[17];
  const float* Wk     = (const float*)d_in[18];
  const float* bk     = (const float*)d_in[19];
  const float* Wv     = (const float*)d_in[20];
  const float* bv     = (const float*)d_in[21];
  const float* We     = (const float*)d_in[22];
  const float* be     = (const float*)d_in[23];
  const float* Wsk    = (const float*)d_in[24];
  const float* bsk    = (const float*)d_in[25];
  const float* wenc_w = (const float*)d_in[26];
  const float* wenc_b = (const float*)d_in[27];
  const float* wx_w   = (const float*)d_in[28];
  const float* wx_b   = (const float*)d_in[29];
  const float* comb_w = (const float*)d_in[30];
  const float* comb_b = (const float*)d_in[31];
  const float* out_w  = (const float*)d_in[32];
  const float* out_b  = (const float*)d_in[33];

  const int N = in_sizes[2];   // node_time
  const int E = in_sizes[3];   // edge_time
  const size_t N64 = (size_t)N * 64;

  float* q    = (float*)d_ws;
  float* k    = q + N64;
  float* v    = k + N64;
  float* rels = v + N64;
  int*   srcs = (int*)(rels + E);
  int*   counts = srcs + E;
  int*   rowptr = counts + N;        // N+1 ints
  int*   next   = rowptr + N + 1;
  int*   bsum   = next + N;          // ceil(N/256) ints (padded)
  float* cbuf   = (float*)(bsum + 4096);
  float* outf   = (float*)d_out;
  float* skip   = outf;  // stage skip in d_out[0:N*64)

  const int B = (N + 255) / 256;

  hipMemsetAsync(counts, 0, (size_t)N * sizeof(int), stream);

  k_precompute<<<1, 64, 0, stream>>>(tf_w, tf_b, deg_w, deg_b, wenc_w, wenc_b, comb_w, cbuf);

  const int ntiles = (N + 63) >> 6;
  k_node_proj<<<ntiles, 256, 0, stream>>>(x, lin_w, lin_b, Wq, bq, Wk, bk, Wv, bv, Wsk, bsk,
                                          be, q, k, v, skip, N);

  const int EB = (E + 255) / 256;
  k_hist<<<EB, 256, 0, stream>>>(ei, counts, E);
  k_scan1<<<B, 256, 0, stream>>>(counts, rowptr, bsum, N);
  k_scan2<<<1, 64, 0, stream>>>(bsum, B);
  k_scan3<<<B, 256, 0, stream>>>(bsum, rowptr, next, N, E);
  k_fill<<<EB, 256, 0, stream>>>(ei, node_time, edge_time, next, srcs, rels, E);

  k_aggregate<<<(N + 3) / 4, 256, 0, stream>>>(rowptr, srcs, rels, q, k, v,
                                               time_w, time_b, We, outf, N);

  k_epilogue<<<2048, 256, 0, stream>>>(nmoti, nod, cbuf, wx_w, wx_b,
                                       comb_w, comb_b, out_w, out_b, y, mask, outf, N);
}